// Round 7
// baseline (984.365 us; speedup 1.0000x reference)
//
#include <hip/hip_runtime.h>

// GATrNet forward, MI355X/gfx950.
// Precision: logits fp32-exact via f16 hi/lo splitting (hn hi/lo planes,
// K=1024 qkv GEMM, q/k stored hi+lo; S = qhi*khi + qlo*khi + qhi*klo).
// Flash r7 (on the r6 packed-LDS-image structure):
//  - alpha-rescale (128 AGPR muls/wave/tile) skipped via per-wave LDS flags
//    when no q-row's running max changed (~94% of tiles; exp2(0)==1 exact).
//  - vp swizzle re-derived for even bank-position coverage (8 lanes/16B pos).
//  - pbuf moved out of the lp overlay -> 3 barriers/tile instead of 4.
//  - qkv epilogue V-store vectorized to 8B (keys rg-consecutive in layout).

typedef unsigned short u16;
typedef unsigned int u32;
typedef __attribute__((ext_vector_type(4))) float f32x4;
typedef __attribute__((ext_vector_type(8))) _Float16 half8;

__device__ inline u16 f2h(float f) {
  _Float16 h = (_Float16)f;
  return __builtin_bit_cast(u16, h);
}
__device__ inline float h2f(u16 u) { return (float)__builtin_bit_cast(_Float16, u); }

// async global->LDS, 16B per lane. LDS dest = wave-uniform base + lane*16.
__device__ inline void async_cp16(const void* g, void* l) {
  __builtin_amdgcn_global_load_lds((const __attribute__((address_space(1))) u32*)g,
                                   (__attribute__((address_space(3))) u32*)l, 16, 0, 0);
}

__device__ inline f32x4 mfma16(half8 a, half8 b, f32x4 c) {
  return __builtin_amdgcn_mfma_f32_16x16x32_f16(a, b, c, 0, 0, 0);
}

// DPP row_ror move within 16-lane rows (reduction domain = lane&15).
template <int CTRL>
__device__ inline float dpp_mv(float v) {
  int i = __builtin_bit_cast(int, v);
  return __builtin_bit_cast(float, __builtin_amdgcn_update_dpp(i, i, CTRL, 0xf, 0xf, false));
}

// INNER_COORDS {0,2,3,4,8,9,10,14} packed 4b each
#define IC_PACK 0xEA984320u

// q buffer row: [q_hi 0,2048) [q_lo 2048,4096)
#define Q_LD 4096
// packed KV block per (b,tile): u16 offsets
//   kp [0,8192):      key*256 + (((d>>3)^(key&7))<<3) + (d&7)
//   lp [8192,16384):  same
//   vp [16384,32768): vd*32 + ((((key>>3)^((vd>>1)&3)))<<3) + (key&7)

// ---------------- weight prep ----------------
__global__ void build_wb_enter(const float* __restrict__ we, const float* __restrict__ blade,
                               float* __restrict__ out) {
  int idx = blockIdx.x * 256 + threadIdx.x;
  if (idx >= 32 * 48 * 16) return;
  int j = idx / 768;
  int rem = idx - j * 768;
  int ix = rem >> 4, y = rem & 15;
  int i = ix >> 4, x = ix & 15;
  float acc = 0.f;
#pragma unroll
  for (int bb = 0; bb < 9; ++bb) acc += we[j * 27 + i * 9 + bb] * blade[bb * 256 + x * 16 + y];
  out[idx] = acc;
}

// WqkvT[n][k] f16, K=1024 (k>=512 duplicates k-512 so GEMM computes (hi+lo)*w).
__global__ void build_wqkvT(const float* __restrict__ wq, const float* __restrict__ wk,
                            const float* __restrict__ wv, const float* __restrict__ blade,
                            u16* __restrict__ out) {
  int idx = blockIdx.x * 256 + threadIdx.x;
  if (idx >= 2816 * 1024) return;
  int k = idx & 1023, n = idx >> 10;
  int kk = k & 511;
  int i = kk >> 4, x = kk & 15;
  const float* w;
  int y;
  float scale = 1.0f;
  if (n < 2048) {
    int j = n >> 3;
    y = (IC_PACK >> ((n & 7) * 4)) & 15;
    w = wq + j * 288 + i * 9;
    scale = 0.09016844005556021f;  // (1/16)*log2(e)
  } else if (n < 2304) {
    int m = n - 2048;
    int j = m >> 3;
    y = (IC_PACK >> ((m & 7) * 4)) & 15;
    w = wk + j * 288 + i * 9;
  } else {
    int m = n - 2304;
    int j = m >> 4;
    y = m & 15;
    w = wv + j * 288 + i * 9;
  }
  float acc = 0.f;
#pragma unroll
  for (int bb = 0; bb < 9; ++bb) acc += w[bb] * blade[bb * 256 + x * 16 + y];
  out[idx] = f2h(acc * scale);
}

// WoutT[n][k] f16: n=(j,y)<512, k=(c,x)<4096
__global__ void build_woutT(const float* __restrict__ wo, const float* __restrict__ blade,
                            u16* __restrict__ out) {
  int idx = blockIdx.x * 256 + threadIdx.x;
  if (idx >= 512 * 4096) return;
  int k = idx & 4095, n = idx >> 12;
  int j = n >> 4, y = n & 15;
  int c = k >> 4, x = k & 15;
  float acc = 0.f;
#pragma unroll
  for (int bb = 0; bb < 9; ++bb) acc += wo[j * 2304 + c * 9 + bb] * blade[bb * 256 + x * 16 + y];
  out[idx] = f2h(acc);
}

// WfinalT[n][k] f16: n=(j,y)<512, k=(i,x)<512
__global__ void build_wfinalT(const float* __restrict__ wf, const float* __restrict__ blade,
                              u16* __restrict__ out) {
  int idx = blockIdx.x * 256 + threadIdx.x;
  if (idx >= 512 * 512) return;
  int k = idx & 511, n = idx >> 9;
  int j = n >> 4, y = n & 15;
  int i = k >> 4, x = k & 15;
  float acc = 0.f;
#pragma unroll
  for (int bb = 0; bb < 9; ++bb) acc += wf[j * 288 + i * 9 + bb] * blade[bb * 256 + x * 16 + y];
  out[idx] = f2h(acc);
}

// ---------------- enter projection + equi_norm ----------------
__global__ __launch_bounds__(256) void enter_norm(const float* __restrict__ x,
                                                  const float* __restrict__ wb,
                                                  float* __restrict__ h, u16* __restrict__ hn) {
  const int tid = threadIdx.x;
  const int tl = tid >> 5, j = tid & 31;
  const int token = blockIdx.x * 8 + tl;
  const float* xp = x + (size_t)token * 48;
  float xv[48];
#pragma unroll
  for (int q = 0; q < 12; ++q) {
    float4 t = ((const float4*)xp)[q];
    xv[q * 4 + 0] = t.x;
    xv[q * 4 + 1] = t.y;
    xv[q * 4 + 2] = t.z;
    xv[q * 4 + 3] = t.w;
  }
  float acc[16] = {};
  const float* wp = wb + j * 768;
#pragma unroll
  for (int t = 0; t < 48; ++t) {
    const float xs = xv[t];
    const float4* w4 = (const float4*)(wp + t * 16);
#pragma unroll
    for (int u = 0; u < 4; ++u) {
      float4 wv = w4[u];
      acc[u * 4 + 0] += xs * wv.x;
      acc[u * 4 + 1] += xs * wv.y;
      acc[u * 4 + 2] += xs * wv.z;
      acc[u * 4 + 3] += xs * wv.w;
    }
  }
  float ip = acc[0] * acc[0] + acc[2] * acc[2] + acc[3] * acc[3] + acc[4] * acc[4] +
             acc[8] * acc[8] + acc[9] * acc[9] + acc[10] * acc[10] + acc[14] * acc[14];
#pragma unroll
  for (int d = 1; d < 32; d <<= 1) ip += __shfl_xor(ip, d, 64);
  const float r = 1.0f / sqrtf(ip * (1.0f / 32.0f));
  float* hp = h + (size_t)token * 512 + j * 16;
#pragma unroll
  for (int u = 0; u < 4; ++u)
    ((float4*)hp)[u] = make_float4(acc[u * 4 + 0], acc[u * 4 + 1], acc[u * 4 + 2], acc[u * 4 + 3]);
  u16 hb[16], lb[16];
#pragma unroll
  for (int y = 0; y < 16; ++y) {
    float sv = acc[y] * r;
    u16 hv = f2h(sv);
    hb[y] = hv;
    lb[y] = f2h(sv - h2f(hv));
  }
  u16* hq = hn + (size_t)token * 1024 + j * 16;
  ((uint4*)hq)[0] = *(const uint4*)&hb[0];
  ((uint4*)hq)[1] = *(const uint4*)&hb[8];
  u16* lq = hq + 512;
  ((uint4*)lq)[0] = *(const uint4*)&lb[0];
  ((uint4*)lq)[1] = *(const uint4*)&lb[8];
}

// ---------------- 128x128 f16 MFMA GEMM, B transposed [N][K] ----------------
// MODE 0: qkv -> q hi/lo rows of Co (ldc=4096); k hi/lo + v into packed kvp
//         blocks (LDS-image layout, swizzle baked in; V stores 8B-vectorized)
// MODE 1: outp -> Co f16 = (acc + res)/256
// MODE 2: final-> Cf fp32 = acc*256
template <int MODE>
__global__ __launch_bounds__(256) void gemm_bt(const u16* __restrict__ A,
                                               const u16* __restrict__ BT, int M, int N, int K,
                                               u16* __restrict__ Co, float* __restrict__ Cf,
                                               const float* __restrict__ res,
                                               u16* __restrict__ kvp, int ldc) {
  __shared__ u16 ltA[4096];  // [128][32], chunk-swizzled
  __shared__ u16 ltB[4096];
  const int tid = threadIdx.x;
  const int lane = tid & 63;
  const int wid = tid >> 6;
  const int quad = lane >> 4, colc = lane & 15;
  const int m0 = blockIdx.y * 128, n0 = blockIdx.x * 128;
  const int wrow = (wid >> 1) * 64, wcol = (wid & 1) * 64;
  f32x4 acc[4][4] = {};
  const int r0 = tid >> 2;
  const int swk = (((tid & 3) ^ ((tid >> 2) & 3)) << 3);
  const u16* Ab = A + (size_t)(m0 + r0) * K + swk;
  const u16* Ab2 = Ab + (size_t)64 * K;
  const u16* Bb = BT + (size_t)(n0 + r0) * K + swk;
  const u16* Bb2 = Bb + (size_t)64 * K;
  const int swr = ((colc & 3) << 3);
  for (int k0 = 0; k0 < K; k0 += 32) {
    __syncthreads();
    async_cp16(Ab + k0, &ltA[tid * 8]);
    async_cp16(Ab2 + k0, &ltA[2048 + tid * 8]);
    async_cp16(Bb + k0, &ltB[tid * 8]);
    async_cp16(Bb2 + k0, &ltB[2048 + tid * 8]);
    __syncthreads();
    half8 af[4], bfr[4];
#pragma unroll
    for (int i2 = 0; i2 < 4; ++i2)
      af[i2] = *(const half8*)&ltA[(wrow + i2 * 16 + colc) * 32 + ((quad << 3) ^ swr)];
#pragma unroll
    for (int j2 = 0; j2 < 4; ++j2)
      bfr[j2] = *(const half8*)&ltB[(wcol + j2 * 16 + colc) * 32 + ((quad << 3) ^ swr)];
#pragma unroll
    for (int i2 = 0; i2 < 4; ++i2)
#pragma unroll
      for (int j2 = 0; j2 < 4; ++j2) acc[i2][j2] = mfma16(af[i2], bfr[j2], acc[i2][j2]);
  }
#pragma unroll
  for (int i2 = 0; i2 < 4; ++i2) {
#pragma unroll
    for (int j2 = 0; j2 < 4; ++j2) {
      const int mb = m0 + wrow + i2 * 16 + quad * 4;
      const int n = n0 + wcol + j2 * 16 + colc;
      if constexpr (MODE == 0) {
        if (n < 2048) {
#pragma unroll
          for (int rg = 0; rg < 4; ++rg) {
            const int m = mb + rg;
            float v = acc[i2][j2][rg];
            u16 hv = f2h(v);
            Co[(size_t)m * ldc + n] = hv;
            Co[(size_t)m * ldc + 2048 + n] = f2h(v - h2f(hv));
          }
        } else if (n < 2304) {
          const int d = n - 2048;
#pragma unroll
          for (int rg = 0; rg < 4; ++rg) {
            const int m = mb + rg;
            int bb2 = m >> 11, s = m & 2047, t = s >> 5, key = s & 31;
            size_t blk = ((size_t)(bb2 * 64 + t)) << 15;
            int off2 = key * 256 + ((((d >> 3) ^ (key & 7)) << 3)) + (d & 7);
            float v = acc[i2][j2][rg];
            u16 hv = f2h(v);
            kvp[blk + off2] = hv;
            kvp[blk + 8192 + off2] = f2h(v - h2f(hv));
          }
        } else {
          const int vd = n - 2304;
          int bb2 = mb >> 11, s0 = mb & 2047, t = s0 >> 5, key0 = s0 & 31;
          size_t blk = ((size_t)(bb2 * 64 + t)) << 15;
          u16 tmp[4];
#pragma unroll
          for (int rg = 0; rg < 4; ++rg) tmp[rg] = f2h(acc[i2][j2][rg]);
          size_t idx =
              blk + 16384 + vd * 32 + ((((key0 >> 3) ^ ((vd >> 1) & 3)) << 3)) + (key0 & 7);
          *(uint2*)&kvp[idx] = *(const uint2*)tmp;
        }
      } else {
#pragma unroll
        for (int rg = 0; rg < 4; ++rg) {
          const int m = mb + rg;
          float v = acc[i2][j2][rg];
          if constexpr (MODE == 1) {
            v += res[(size_t)m * ldc + n];
            Co[(size_t)m * ldc + n] = f2h(v * (1.0f / 256.0f));
          } else {
            Cf[(size_t)m * ldc + n] = v * 256.0f;
          }
        }
      }
    }
  }
}

// ---------------- flash attention ----------------
// grid (qblock=32, head=8, batch=4), 256 thr. Per tile: linear 64KB async
// stage of the packed (kp|lp|vp) LDS image; S (48 MFMAs, 4 chains) from
// kp/lp; DPP softmax; pbuf (separate region) publishes P; PV (32 MFMAs)
// from vp with flag-gated alpha rescale. 3 barriers/tile, zero global loads.
__global__ __launch_bounds__(256, 2) void flash_attn(const u16* __restrict__ qbuf,
                                                     const u16* __restrict__ kvp,
                                                     u16* __restrict__ out) {
  __shared__ u16 lds[35600];
  u16* kp = lds;                                   // [32 keys][256 d] swizzled
  u16* lp = lds + 8192;                            // k_lo, same layout
  u16* vp = lds + 16384;                           // [512 vd][32 keys] swizzled
  u16* pbuf = lds + 32768;                         // [64 qrow][40] (pad 40)
  float* alpha_s = (float*)(lds + 35328);          // 64 floats
  float* l_s = (float*)(lds + 35456);              // 64 floats
  int* flg = (int*)(lds + 35584);                  // 4 per-wave rescale flags
  const int tid = threadIdx.x, lane = tid & 63, wid = tid >> 6;
  const int quad = lane >> 4, colc = lane & 15;
  const int b = blockIdx.z, h = blockIdx.y, qb = blockIdx.x;
  half8 qh[8], ql[8];
  {
    const u16* qr = qbuf + (size_t)(b * 2048 + qb * 64 + wid * 16 + colc) * Q_LD + h * 8;
#pragma unroll
    for (int kb = 0; kb < 8; ++kb) {
      qh[kb] = *(const half8*)(qr + (kb * 4 + quad) * 64);
      ql[kb] = *(const half8*)(qr + 2048 + (kb * 4 + quad) * 64);
    }
  }
  f32x4 oacc[4][8] = {};
  float mrun[4], lrun[4];
#pragma unroll
  for (int rg = 0; rg < 4; ++rg) {
    mrun[rg] = -1e30f;
    lrun[rg] = 0.f;
  }
  const u16* kvb = kvp + ((size_t)(b * 64) << 15);
  const int x0 = colc & 7;
  for (int it = 0; it < 64; ++it) {
    __syncthreads();  // B0: prev tile's PV reads (vp/pbuf/alpha) complete
    {
      const u16* src = kvb + ((size_t)it << 15);
#pragma unroll
      for (int c = 0; c < 16; ++c) {
        int e = c * 256 + tid;
        async_cp16(src + e * 8, &lds[e * 8]);
      }
    }
    __syncthreads();  // B1: stage drained
    // S [16q x 32k], fp32-exact, 4 accumulation chains
    f32x4 s0a = {}, s0b = {}, s1a = {}, s1b = {};
#pragma unroll
    for (int kb = 0; kb < 8; ++kb) {
      const int sw = (((kb * 4 + quad) ^ x0) << 3);
      half8 khi0 = *(const half8*)&kp[colc * 256 + sw];
      half8 khi1 = *(const half8*)&kp[(16 + colc) * 256 + sw];
      half8 klo0 = *(const half8*)&lp[colc * 256 + sw];
      half8 klo1 = *(const half8*)&lp[(16 + colc) * 256 + sw];
      s0a = mfma16(qh[kb], khi0, s0a);
      s0b = mfma16(ql[kb], khi0, s0b);
      s1a = mfma16(qh[kb], khi1, s1a);
      s1b = mfma16(ql[kb], khi1, s1b);
      if (kb & 1) {
        s0b = mfma16(qh[kb], klo0, s0b);
        s1b = mfma16(qh[kb], klo1, s1b);
      } else {
        s0a = mfma16(qh[kb], klo0, s0a);
        s1a = mfma16(qh[kb], klo1, s1a);
      }
    }
    f32x4 sfr[2];
    sfr[0] = s0a + s0b;
    sfr[1] = s1a + s1b;
    // online softmax (exp2 domain), DPP row_ror butterflies over colc
    float mx[4];
#pragma unroll
    for (int rg = 0; rg < 4; ++rg) mx[rg] = fmaxf(sfr[0][rg], sfr[1][rg]);
#pragma unroll
    for (int rg = 0; rg < 4; ++rg) mx[rg] = fmaxf(mx[rg], dpp_mv<0x121>(mx[rg]));
#pragma unroll
    for (int rg = 0; rg < 4; ++rg) mx[rg] = fmaxf(mx[rg], dpp_mv<0x122>(mx[rg]));
#pragma unroll
    for (int rg = 0; rg < 4; ++rg) mx[rg] = fmaxf(mx[rg], dpp_mv<0x124>(mx[rg]));
#pragma unroll
    for (int rg = 0; rg < 4; ++rg) mx[rg] = fmaxf(mx[rg], dpp_mv<0x128>(mx[rg]));
    float al[4], pv0[4], pv1[4], rs[4];
#pragma unroll
    for (int rg = 0; rg < 4; ++rg) {
      float mn = fmaxf(mrun[rg], mx[rg]);
      al[rg] = exp2f(mrun[rg] - mn);
      mrun[rg] = mn;
      pv0[rg] = exp2f(sfr[0][rg] - mn);
      pv1[rg] = exp2f(sfr[1][rg] - mn);
      rs[rg] = pv0[rg] + pv1[rg];
    }
#pragma unroll
    for (int rg = 0; rg < 4; ++rg) rs[rg] += dpp_mv<0x121>(rs[rg]);
#pragma unroll
    for (int rg = 0; rg < 4; ++rg) rs[rg] += dpp_mv<0x122>(rs[rg]);
#pragma unroll
    for (int rg = 0; rg < 4; ++rg) rs[rg] += dpp_mv<0x124>(rs[rg]);
#pragma unroll
    for (int rg = 0; rg < 4; ++rg) rs[rg] += dpp_mv<0x128>(rs[rg]);
    const int prow = wid * 16 + quad * 4;
#pragma unroll
    for (int rg = 0; rg < 4; ++rg) {
      lrun[rg] = lrun[rg] * al[rg] + rs[rg];
      pbuf[(prow + rg) * 40 + colc] = f2h(pv0[rg]);
      pbuf[(prow + rg) * 40 + 16 + colc] = f2h(pv1[rg]);
    }
    {
      // per-wave "any alpha != 1" flag (this wave's lanes cover its 16 rows)
      float nd = __builtin_fabsf(al[0] - 1.f) + __builtin_fabsf(al[1] - 1.f) +
                 __builtin_fabsf(al[2] - 1.f) + __builtin_fabsf(al[3] - 1.f);
      int own = __any(nd != 0.f);
      if (lane == 0) flg[wid] = own;
    }
    if (colc == 0) {
#pragma unroll
      for (int rg = 0; rg < 4; ++rg) alpha_s[prow + rg] = al[rg];
    }
    __syncthreads();  // B3: pbuf/alpha/flags published
    // PV: this wave's 128 v-dims, all 64 q-rows
    half8 vf[8];
#pragma unroll
    for (int vb = 0; vb < 8; ++vb) {
      const int vd = wid * 128 + vb * 16 + colc;
      vf[vb] = *(const half8*)&vp[vd * 32 + ((quad ^ ((vd >> 1) & 3)) << 3)];
    }
    half8 pf[4];
#pragma unroll
    for (int pa = 0; pa < 4; ++pa) pf[pa] = *(const half8*)&pbuf[(pa * 16 + colc) * 40 + quad * 8];
    const int need = flg[0] | flg[1] | flg[2] | flg[3];
    if (need) {
      float av[4][4];
#pragma unroll
      for (int pa = 0; pa < 4; ++pa)
#pragma unroll
        for (int rg = 0; rg < 4; ++rg) av[pa][rg] = alpha_s[pa * 16 + quad * 4 + rg];
#pragma unroll
      for (int pa = 0; pa < 4; ++pa)
#pragma unroll
        for (int vb = 0; vb < 8; ++vb)
#pragma unroll
          for (int rg = 0; rg < 4; ++rg) oacc[pa][vb][rg] *= av[pa][rg];
    }
#pragma unroll
    for (int vb = 0; vb < 8; ++vb)
#pragma unroll
      for (int pa = 0; pa < 4; ++pa) oacc[pa][vb] = mfma16(pf[pa], vf[vb], oacc[pa][vb]);
  }
  {
    const int prow = wid * 16 + quad * 4;
    if (colc == 0) {
#pragma unroll
      for (int rg = 0; rg < 4; ++rg) l_s[prow + rg] = lrun[rg];
    }
  }
  __syncthreads();
  u16* ob = out + ((size_t)b * 2048 + qb * 64) * 4096 + h * 512 + wid * 128;
#pragma unroll
  for (int pa = 0; pa < 4; ++pa) {
    float li[4];
#pragma unroll
    for (int rg = 0; rg < 4; ++rg) li[rg] = 1.0f / l_s[pa * 16 + quad * 4 + rg];
#pragma unroll
    for (int vb = 0; vb < 8; ++vb)
#pragma unroll
      for (int rg = 0; rg < 4; ++rg)
        ob[(size_t)(pa * 16 + quad * 4 + rg) * 4096 + vb * 16 + colc] =
            f2h(oacc[pa][vb][rg] * li[rg]);
  }
}

// ---------------- launcher ----------------
extern "C" void kernel_launch(void* const* d_in, const int* in_sizes, int n_in, void* d_out,
                              int out_size, void* d_ws, size_t ws_size, hipStream_t stream) {
  const float* x = (const float*)d_in[0];
  const float* blade = (const float*)d_in[1];
  const float* w_enter = (const float*)d_in[2];
  const float* w_q = (const float*)d_in[3];
  const float* w_k = (const float*)d_in[4];
  const float* w_v = (const float*)d_in[5];
  const float* w_out = (const float*)d_in[6];
  const float* w_final = (const float*)d_in[7];
  float* out = (float*)d_out;

  char* ws = (char*)d_ws;
  size_t off = 0;
  auto alloc = [&](size_t bytes) {
    void* p = ws + off;
    off = (off + bytes + 255) & ~(size_t)255;
    return p;
  };
  float* wb_enter = (float*)alloc((size_t)32 * 48 * 16 * 4);
  u16* wqkvT = (u16*)alloc((size_t)2816 * 1024 * 2);
  u16* woutT = (u16*)alloc((size_t)512 * 4096 * 2);
  u16* wfinT = (u16*)alloc((size_t)512 * 512 * 2);
  float* hbuf = (float*)alloc((size_t)8192 * 512 * 4);
  u16* hn2 = (u16*)alloc((size_t)8192 * 1024 * 2);
  u16* qbuf = (u16*)alloc((size_t)8192 * Q_LD * 2);
  u16* kvp = (u16*)alloc((size_t)4 * 64 * 32768 * 2);
  u16* attno = (u16*)alloc((size_t)8192 * 4096 * 2);
  u16* h2 = (u16*)alloc((size_t)8192 * 512 * 2);

  build_wb_enter<<<96, 256, 0, stream>>>(w_enter, blade, wb_enter);
  build_wqkvT<<<11264, 256, 0, stream>>>(w_q, w_k, w_v, blade, wqkvT);
  build_woutT<<<8192, 256, 0, stream>>>(w_out, blade, woutT);
  build_wfinalT<<<1024, 256, 0, stream>>>(w_final, blade, wfinT);
  enter_norm<<<1024, 256, 0, stream>>>(x, wb_enter, hbuf, hn2);
  gemm_bt<0><<<dim3(22, 64), 256, 0, stream>>>(hn2, wqkvT, 8192, 2816, 1024, qbuf, nullptr,
                                               nullptr, kvp, Q_LD);
  flash_attn<<<dim3(32, 8, 4), 256, 0, stream>>>(qbuf, kvp, attno);
  gemm_bt<1><<<dim3(4, 64), 256, 0, stream>>>(attno, woutT, 8192, 512, 4096, h2, nullptr, hbuf,
                                              nullptr, 512);
  gemm_bt<2><<<dim3(4, 64), 256, 0, stream>>>(h2, wfinT, 8192, 512, 512, nullptr, out, nullptr,
                                              nullptr, 512);
}